// Round 1
// 276.466 us; speedup vs baseline: 1.0847x; 1.0847x over previous
//
#include <hip/hip_runtime.h>
#include <hip/hip_bf16.h>

#define NN 50000
#define NPAD 53248              // 13 * 4096, scan padding
#define EE 800000
#define DIM 256
#define NEG_SLOPE 0.2f
#define LOG2E 1.44269504088896f

#define GEMM_BLOCKS 1564        // 391 * 4
#define FILL_BLOCKS 3125
#define CNT_BLOCKS  3125
#define CVT_BLOCKS  12500
#define WT_BLOCKS   512

typedef __attribute__((ext_vector_type(8))) short short8;
typedef __attribute__((ext_vector_type(4))) float f32x4;

__device__ __forceinline__ unsigned short f2bf(float f) {
    unsigned u = __float_as_uint(f);
    unsigned r = (u + 0x7fffu + ((u >> 16) & 1u)) >> 16;   // RNE
    return (unsigned short)r;
}
__device__ __forceinline__ float bf2f(unsigned short h) {
    return __uint_as_float(((unsigned)h) << 16);
}

// 8-lane sum via DPP (VALU pipe only — no ds_swizzle LDS round trips).
// quad_perm[1,0,3,2] (0xB1) ≡ xor1, quad_perm[2,3,0,1] (0x4E) ≡ xor2,
// row_half_mirror (0x141) fetches the other quad's (identical) quad-sum,
// so the result is bitwise identical to the shfl_xor 1/2/4 butterfly.
__device__ __forceinline__ float red8(float s) {
    int t;
    t = __builtin_amdgcn_update_dpp(0, __float_as_int(s), 0xB1, 0xF, 0xF, true);
    s += __int_as_float(t);
    t = __builtin_amdgcn_update_dpp(0, __float_as_int(s), 0x4E, 0xF, 0xF, true);
    s += __int_as_float(t);
    t = __builtin_amdgcn_update_dpp(0, __float_as_int(s), 0x141, 0xF, 0xF, true);
    s += __int_as_float(t);
    return s;
}

// ---------------------------------------------------------------------------
// K_A (fused): blocks [0,3125) per-dst degree count + per-edge rank (atomic-
// latency-bound) overlapped with [3125,15625) x->bf16 cvt and [15625,16137)
// Wt build (HBM-bound). cnt is zeroed by a preceding memset.
// ---------------------------------------------------------------------------
__global__ __launch_bounds__(256) void k_prep_count(
    const float* __restrict__ x, const float* __restrict__ Wl,
    const float* __restrict__ Wr, const int* __restrict__ ei,
    unsigned short* __restrict__ xb, unsigned short* __restrict__ wt,
    int* __restrict__ cnt, int* __restrict__ rank)
{
    int b = blockIdx.x;
    if (b < CNT_BLOCKS) {                                  // degree count
        int e = b * 256 + threadIdx.x;
        if (e < EE) {
            int dst = ei[EE + e];
            rank[e] = atomicAdd(&cnt[dst], 1);
        }
    } else if (b < CNT_BLOCKS + CVT_BLOCKS) {              // x -> bf16
        int i = ((b - CNT_BLOCKS) * 256 + threadIdx.x) * 4;
        float4 v = *(const float4*)(x + i);
        ushort4 o;
        o.x = f2bf(v.x); o.y = f2bf(v.y); o.z = f2bf(v.z); o.w = f2bf(v.w);
        *(ushort4*)(xb + i) = o;
    } else {                                               // Wt build
        int idx = (b - CNT_BLOCKS - CVT_BLOCKS) * 256 + threadIdx.x;
        int n = idx >> 8, k = idx & 255;
        float v = (n < 256) ? Wl[k * 256 + n] : Wr[k * 256 + (n - 256)];
        wt[idx] = f2bf(v);
    }
}

// ---------------------------------------------------------------------------
// K2: exclusive prefix sum of cnt -> row_start (int4-vectorized, 1 block).
// All 13 passes' loads hoisted up front: the serial carry chain no longer
// pays 13 back-to-back global-load latencies.
// ---------------------------------------------------------------------------
__global__ __launch_bounds__(1024) void k_scan(
    const int* __restrict__ cnt, int* __restrict__ row_start)
{
    __shared__ int wsum[16];
    int tid = threadIdx.x, lane = tid & 63, wid = tid >> 6;
    int4 v[13];
#pragma unroll
    for (int p = 0; p < 13; ++p)
        v[p] = *(const int4*)(cnt + p * 4096 + tid * 4);
    int carry = 0;
#pragma unroll
    for (int p = 0; p < 13; ++p) {
        int4 vv = v[p];
        int tsum = vv.x + vv.y + vv.z + vv.w;
        int s = tsum;
#pragma unroll
        for (int off = 1; off < 64; off <<= 1) {
            int t = __shfl_up(s, off, 64);
            if (lane >= off) s += t;
        }
        if (lane == 63) wsum[wid] = s;
        __syncthreads();
        int wpre = 0, tot = 0;
#pragma unroll
        for (int w = 0; w < 16; ++w) {
            int xv = wsum[w];
            tot += xv;
            if (w < wid) wpre += xv;
        }
        int ex = carry + wpre + (s - tsum);
        int4 o;
        o.x = ex;
        o.y = o.x + vv.x;
        o.z = o.y + vv.y;
        o.w = o.z + vv.z;
        *(int4*)(row_start + p * 4096 + tid * 4) = o;
        carry += tot;
        __syncthreads();
    }
}

// ---------------------------------------------------------------------------
// K_B (fused): blocks [0,1564) MFMA GEMM xlr = xb @ [Wl|Wr]^T (compute-bound)
// overlapped with [1564,4689) CSR fill (scattered-write-bound, NO atomics).
// Edge record packed to 8B: {src:i32, a1:bf16|a0:bf16}.
// ---------------------------------------------------------------------------
__global__ __launch_bounds__(256) void k_gemm_fill(
    const unsigned short* __restrict__ xb, const unsigned short* __restrict__ wt,
    const int* __restrict__ ei, const float* __restrict__ ea,
    const int* __restrict__ row_start, const int* __restrict__ rank,
    unsigned short* __restrict__ xlr, uint2* __restrict__ edge_rec)
{
    __shared__ short sAB[8192];                 // A: [0,4096) B: [4096,8192)
    int tid = threadIdx.x;

    if (blockIdx.x >= GEMM_BLOCKS) {            // ---- CSR fill ----
        int e = (blockIdx.x - GEMM_BLOCKS) * 256 + tid;
        if (e < EE) {
            int src = ei[e];
            int dst = ei[EE + e];
            float2 a = *(const float2*)(ea + 2 * e);
            int pos = row_start[dst] + rank[e];
            unsigned packed = ((unsigned)f2bf(a.y) << 16) | f2bf(a.x);
            edge_rec[pos] = make_uint2((unsigned)src, packed);
        }
        return;
    }

    // ---- GEMM (unchanged, verified) ----
    int wid = tid >> 6, lane = tid & 63;
    int mt = blockIdx.x >> 2, nt = blockIdx.x & 3;
    int mBase = mt * 128, nBase = nt * 128;
    int wm = (wid & 1) * 64, wn = (wid >> 1) * 64;
    int q = lane >> 4, mh = lane & 15;

    f32x4 acc[4][4];
#pragma unroll
    for (int i = 0; i < 4; ++i)
#pragma unroll
        for (int j = 0; j < 4; ++j)
            acc[i][j] = (f32x4){0.f, 0.f, 0.f, 0.f};

    int aoff[4], boff[4];
#pragma unroll
    for (int f = 0; f < 4; ++f) {
        int r  = wm + f * 16 + mh;
        aoff[f] = (r * 4 + (q ^ (r & 3))) * 8;
        int nl = wn + f * 16 + mh;
        boff[f] = 4096 + (nl * 4 + (q ^ (nl & 3))) * 8;
    }

    for (int k0 = 0; k0 < 256; k0 += 32) {
        __syncthreads();
#pragma unroll
        for (int it = 0; it < 4; ++it) {
            int L = it * 256 + tid;
            const unsigned short* g;
            if (L < 512) {
                int r  = L >> 2;
                int qq = (L & 3) ^ (r & 3);
                int grow = mBase + r;
                if (grow > NN - 1) grow = NN - 1;
                g = xb + (size_t)grow * 256 + k0 + qq * 8;
            } else {
                int LB = L - 512;
                int nl = LB >> 2;
                int qq = (LB & 3) ^ (nl & 3);
                g = wt + (size_t)(nBase + nl) * 256 + k0 + qq * 8;
            }
            short* lp = sAB + (it * 256 + wid * 64) * 8;
            __builtin_amdgcn_global_load_lds(
                (const __attribute__((address_space(1))) void*)g,
                (__attribute__((address_space(3))) void*)lp, 16, 0, 0);
        }
        __syncthreads();

        short8 af[4], bfr[4];
#pragma unroll
        for (int f = 0; f < 4; ++f) af[f]  = *(const short8*)(sAB + aoff[f]);
#pragma unroll
        for (int f = 0; f < 4; ++f) bfr[f] = *(const short8*)(sAB + boff[f]);
#pragma unroll
        for (int i = 0; i < 4; ++i)
#pragma unroll
            for (int j = 0; j < 4; ++j)
                acc[i][j] = __builtin_amdgcn_mfma_f32_16x16x32_bf16(
                    af[i], bfr[j], acc[i][j], 0, 0, 0);
    }

#pragma unroll
    for (int i = 0; i < 4; ++i)
#pragma unroll
        for (int j = 0; j < 4; ++j)
#pragma unroll
            for (int r = 0; r < 4; ++r) {
                int row = mBase + wm + i * 16 + q * 4 + r;
                if (row < NN) {
                    int col = nBase + wn + j * 16 + mh;
                    xlr[(size_t)row * 512 + col] = f2bf(acc[i][j][r]);
                }
            }
}

// ---------------------------------------------------------------------------
// K5: fused attention — one wave per dst node.
// v2: chunk-cached edge records (one coalesced dwordx2 load per <=64 edges;
// per-edge readlane -> SGPR src + attrs, SALU address math), group-of-4
// register-renamed gather pipeline (prefetch distance 4, zero rotation movs,
// uniform-branch guards), DPP-based 8-lane dot reduction (no LDS swizzles).
// edge_rec has a 64-record zeroed pad so prefetch needs no clamps.
// ---------------------------------------------------------------------------
__global__ __launch_bounds__(256) void k_attn(
    const unsigned short* __restrict__ xlr, const int* __restrict__ row_start,
    const uint2* __restrict__ edge_rec, const float* __restrict__ W_e,
    const float* __restrict__ att, const float* __restrict__ bias,
    float* __restrict__ out)
{
    int n = __builtin_amdgcn_readfirstlane(blockIdx.x * 4 + (threadIdx.x >> 6));
    if (n >= NN) return;
    int lane = threadIdx.x & 63;
    int j = lane * 4;

    const unsigned short* nrow = xlr + ((size_t)n << 9);
    ushort4 xru = *(const ushort4*)(nrow + 256 + j);
    float4 xr4 = make_float4(bf2f(xru.x), bf2f(xru.y), bf2f(xru.z), bf2f(xru.w));
    float4 att4 = *(const float4*)(att + j);
    att4.x *= LOG2E; att4.y *= LOG2E; att4.z *= LOG2E; att4.w *= LOG2E;
    float4 a02  = make_float4(att4.x * NEG_SLOPE, att4.y * NEG_SLOPE,
                              att4.z * NEG_SLOPE, att4.w * NEG_SLOPE);
    float4 we0  = *(const float4*)(W_e + j);
    float4 we1  = *(const float4*)(W_e + 256 + j);

    int rs = __builtin_amdgcn_readfirstlane(row_start[n]);
    int cn = __builtin_amdgcn_readfirstlane(row_start[n + 1]) - rs;

    float D = 0.0f, la0 = 0.0f, la1 = 0.0f;
    float4 acc = make_float4(0.f, 0.f, 0.f, 0.f);

    auto body = [&](ushort4 xu, float a0, float a1) {
        float4 xl4 = make_float4(bf2f(xu.x), bf2f(xu.y), bf2f(xu.z), bf2f(xu.w));
        float m0 = fmaf(a0, we0.x, fmaf(a1, we1.x, xl4.x + xr4.x));
        float m1 = fmaf(a0, we0.y, fmaf(a1, we1.y, xl4.y + xr4.y));
        float m2 = fmaf(a0, we0.z, fmaf(a1, we1.z, xl4.z + xr4.z));
        float m3 = fmaf(a0, we0.w, fmaf(a1, we1.w, xl4.w + xr4.w));
        float p0 = (m0 > 0.f) ? att4.x : a02.x;   // lrelu folded into dot
        float p1 = (m1 > 0.f) ? att4.y : a02.y;
        float p2 = (m2 > 0.f) ? att4.z : a02.z;
        float p3 = (m3 > 0.f) ? att4.w : a02.w;
        float s = fmaf(m0, p0, fmaf(m1, p1, fmaf(m2, p2, m3 * p3)));
        s = red8(s);                              // DPP, VALU-pipe only
        float w = __builtin_amdgcn_exp2f(s);      // e^(s/log2e) == 2^s here
        D += w;
        acc.x = fmaf(w, xl4.x, acc.x);
        acc.y = fmaf(w, xl4.y, acc.y);
        acc.z = fmaf(w, xl4.z, acc.z);
        acc.w = fmaf(w, xl4.w, acc.w);
    };

    int done = 0;
    while (done < cn) {
        int m = cn - done; if (m > 64) m = 64;
        // one coalesced load pulls up to 64 records into lane registers
        int ridx = rs + done + lane;
        if (ridx > EE + 63) ridx = EE + 63;       // zeroed pad region
        uint2 rc = edge_rec[ridx];
        int rcx = (int)rc.x, rca = (int)rc.y;

        auto gat = [&](int k) -> ushort4 {        // k is wave-uniform
            unsigned sidx = (unsigned)__builtin_amdgcn_readlane(rcx, k);
            return *(const ushort4*)(xlr + ((size_t)sidx << 9) + j);
        };
        auto proc = [&](ushort4 xu, int k) {
            unsigned pk = (unsigned)__builtin_amdgcn_readlane(rca, k);
            float a0 = __uint_as_float(pk << 16);
            float a1 = __uint_as_float(pk & 0xffff0000u);
            la0 += a0; la1 += a1;
            body(xu, a0, a1);
        };

        ushort4 x0 = gat(0), x1 = gat(1), x2 = gat(2), x3 = gat(3);
        for (int i = 0; i < m; i += 4) {
            proc(x0, i);
            if (i + 4 < m) x0 = gat(i + 4);
            if (i + 1 < m) { proc(x1, i + 1); if (i + 5 < m) x1 = gat(i + 5); }
            if (i + 2 < m) { proc(x2, i + 2); if (i + 6 < m) x2 = gat(i + 6); }
            if (i + 3 < m) { proc(x3, i + 3); if (i + 7 < m) x3 = gat(i + 7); }
        }
        done += m;
    }

    // self loop last, with mean edge attr of incoming edges
    float invc = 1.0f / fmaxf((float)cn, 1.0f);
    ushort4 xs = *(const ushort4*)(nrow + j);
    body(xs, la0 * invc, la1 * invc);

    float invD = 1.0f / D;
    float4 b4 = *(const float4*)(bias + j);
    float4 o;
    o.x = fmaf(acc.x, invD, b4.x);
    o.y = fmaf(acc.y, invD, b4.y);
    o.z = fmaf(acc.z, invD, b4.z);
    o.w = fmaf(acc.w, invD, b4.w);
    *(float4*)(out + (size_t)n * 256 + j) = o;
}

// ---------------------------------------------------------------------------
extern "C" void kernel_launch(void* const* d_in, const int* in_sizes, int n_in,
                              void* d_out, int out_size, void* d_ws, size_t ws_size,
                              hipStream_t stream)
{
    const float* x    = (const float*)d_in[0];
    const int*   ei   = (const int*)  d_in[1];
    const float* ea   = (const float*)d_in[2];
    const float* Wl   = (const float*)d_in[3];
    const float* Wr   = (const float*)d_in[4];
    const float* We   = (const float*)d_in[5];
    const float* att  = (const float*)d_in[6];
    const float* bias = (const float*)d_in[7];
    float* out = (float*)d_out;

    char* ws = (char*)d_ws;
    size_t off = 0;
    unsigned short* xlr = (unsigned short*)(ws + off); off += (size_t)NN * 512 * 2;  // 51.2 MB
    unsigned short* xb  = (unsigned short*)(ws + off); off += (size_t)NN * 256 * 2;  // 25.6 MB
    uint2*  edge_rec    = (uint2*)(ws + off);          off += (size_t)(EE + 64) * 8; //  6.4 MB (+pad)
    int*    rank        = (int*)(ws + off);            off += (size_t)EE * 4;        //  3.2 MB
    unsigned short* wt  = (unsigned short*)(ws + off); off += (size_t)512 * 256 * 2; // 256 KB
    int*    cnt         = (int*)(ws + off);            off += (size_t)NPAD * 4;
    int*    row_st      = (int*)(ws + off);            off += (size_t)NPAD * 4;
    // total ~87 MB

    hipMemsetAsync(cnt, 0, NPAD * sizeof(int), stream);
    hipMemsetAsync(edge_rec + EE, 0, 64 * sizeof(uint2), stream);  // prefetch pad

    k_prep_count<<<CNT_BLOCKS + CVT_BLOCKS + WT_BLOCKS, 256, 0, stream>>>(
        x, Wl, Wr, ei, xb, wt, cnt, rank);
    k_scan      <<<1, 1024, 0, stream>>>(cnt, row_st);
    k_gemm_fill <<<GEMM_BLOCKS + FILL_BLOCKS, 256, 0, stream>>>(
        xb, wt, ei, ea, row_st, rank, xlr, edge_rec);
    k_attn      <<<12500, 256, 0, stream>>>(
        xlr, row_st, edge_rec, We, att, bias, out);
}